// Round 1
// baseline (305.710 us; speedup 1.0000x reference)
//
#include <hip/hip_runtime.h>
#include <hip/hip_bf16.h>

#define D 256
#define TWOD 512

// ---------- helpers ----------
__device__ __forceinline__ float bf2f(unsigned short u) {
    unsigned int x = ((unsigned int)u) << 16;
    return __uint_as_float(x);
}
__device__ __forceinline__ unsigned short f2bf(float f) {
    unsigned int x = __float_as_uint(f);
    // round-to-nearest-even
    unsigned int r = (x + 0x7fffu + ((x >> 16) & 1u)) >> 16;
    return (unsigned short)r;
}

// ---------- Kernel 1: node projection GEMM ----------
// C[u, j'] = sum_k z[u,k] * W[k,j'],  j' in [0,512)
//   W[k,j'] = (j' < 256) ? w1[j'*512 + k] : w1[(j'-256)*512 + 256 + k]
// C stored as bf16, row stride 512. C[u, 0:256] = A-half, C[u, 256:512] = B-half.
__global__ __launch_bounds__(256) void node_proj_kernel(
    const float* __restrict__ z, const float* __restrict__ w1,
    unsigned short* __restrict__ C, int M)
{
    __shared__ float As[16][65];
    __shared__ float Bs[16][65];

    const int tid = threadIdx.x;
    const int m0 = blockIdx.x * 64;
    const int n0 = blockIdx.y * 64;

    const int r  = tid >> 2;         // 0..63 (row within tile for loads)
    const int kq = (tid & 3) * 4;    // 0,4,8,12

    const int tm = (tid & 15) * 4;   // output row offset (within tile)
    const int tn = (tid >> 4) * 4;   // output col offset

    float acc[4][4] = {};

    // B-source row pointer for this thread's j' = n0 + r
    const float* w1base = (n0 < D) ? (w1 + (size_t)(n0 + r) * TWOD)
                                   : (w1 + (size_t)(n0 - D + r) * TWOD + D);
    const bool arow_ok = (m0 + r) < M;
    const float* zrow = z + (size_t)(m0 + r) * D;

    for (int kb = 0; kb < D; kb += 16) {
        float4 av = make_float4(0.f, 0.f, 0.f, 0.f);
        if (arow_ok) av = *(const float4*)(zrow + kb + kq);
        As[kq + 0][r] = av.x; As[kq + 1][r] = av.y;
        As[kq + 2][r] = av.z; As[kq + 3][r] = av.w;

        float4 bv = *(const float4*)(w1base + kb + kq);
        Bs[kq + 0][r] = bv.x; Bs[kq + 1][r] = bv.y;
        Bs[kq + 2][r] = bv.z; Bs[kq + 3][r] = bv.w;

        __syncthreads();

        #pragma unroll
        for (int k = 0; k < 16; ++k) {
            float a[4], b[4];
            #pragma unroll
            for (int i = 0; i < 4; ++i) a[i] = As[k][tm + i];
            #pragma unroll
            for (int j = 0; j < 4; ++j) b[j] = Bs[k][tn + j];
            #pragma unroll
            for (int i = 0; i < 4; ++i)
                #pragma unroll
                for (int j = 0; j < 4; ++j)
                    acc[i][j] = fmaf(a[i], b[j], acc[i][j]);
        }
        __syncthreads();
    }

    #pragma unroll
    for (int i = 0; i < 4; ++i) {
        const int row = m0 + tm + i;
        if (row < M) {
            ushort4 pk;
            pk.x = f2bf(acc[i][0]);
            pk.y = f2bf(acc[i][1]);
            pk.z = f2bf(acc[i][2]);
            pk.w = f2bf(acc[i][3]);
            *(ushort4*)(C + (size_t)row * TWOD + n0 + tn) = pk;
        }
    }
}

// ---------- Kernel 2: per-edge relu-dot ----------
// out[e] = sum_j relu(A[u,j] + B[v,j] + b1[j]) * w2[j] + b2
__global__ __launch_bounds__(256) void edge_kernel(
    const int* __restrict__ ei, const unsigned short* __restrict__ C,
    const float* __restrict__ b1, const float* __restrict__ w2,
    const float* __restrict__ b2, float* __restrict__ out, int E)
{
    const int lane = threadIdx.x & 63;
    const int wid  = (blockIdx.x * blockDim.x + threadIdx.x) >> 6;
    const int nw   = (gridDim.x * blockDim.x) >> 6;
    const int j0   = lane * 4;

    const float4 w2v = *(const float4*)(w2 + j0);
    const float4 b1v = *(const float4*)(b1 + j0);
    const float  b2s = b2[0];

    for (int e = wid; e < E; e += nw) {
        const int u = ei[e];
        const int v = ei[E + e];

        const ushort4 ua = *(const ushort4*)(C + (size_t)u * TWOD + j0);
        const ushort4 ub = *(const ushort4*)(C + (size_t)v * TWOD + D + j0);

        float s = 0.f;
        s += fmaxf(bf2f(ua.x) + bf2f(ub.x) + b1v.x, 0.f) * w2v.x;
        s += fmaxf(bf2f(ua.y) + bf2f(ub.y) + b1v.y, 0.f) * w2v.y;
        s += fmaxf(bf2f(ua.z) + bf2f(ub.z) + b1v.z, 0.f) * w2v.z;
        s += fmaxf(bf2f(ua.w) + bf2f(ub.w) + b1v.w, 0.f) * w2v.w;

        #pragma unroll
        for (int off = 32; off; off >>= 1)
            s += __shfl_xor(s, off);

        if (lane == 0) out[e] = s + b2s;
    }
}

extern "C" void kernel_launch(void* const* d_in, const int* in_sizes, int n_in,
                              void* d_out, int out_size, void* d_ws, size_t ws_size,
                              hipStream_t stream) {
    const float* z  = (const float*)d_in[0];
    const int*   ei = (const int*)d_in[1];
    const float* w1 = (const float*)d_in[2];
    const float* b1 = (const float*)d_in[3];
    const float* w2 = (const float*)d_in[4];
    const float* b2 = (const float*)d_in[5];
    float* out = (float*)d_out;

    const int M = in_sizes[0] / D;   // 50000 nodes
    const int E = in_sizes[1] / 2;   // 320000 edges

    unsigned short* C = (unsigned short*)d_ws;  // M*512 bf16 = 51.2 MB

    dim3 g1((M + 63) / 64, TWOD / 64);
    node_proj_kernel<<<g1, 256, 0, stream>>>(z, w1, C, M);

    edge_kernel<<<4096, 256, 0, stream>>>(ei, C, b1, w2, b2, out, E);
}

// Round 2
// 138.893 us; speedup vs baseline: 2.2010x; 2.2010x over previous
//
#include <hip/hip_runtime.h>
#include <hip/hip_bf16.h>

#define D 256
#define TWOD 512

typedef __attribute__((ext_vector_type(8))) __bf16 bf16x8;
typedef __attribute__((ext_vector_type(4))) float f32x4;
typedef __attribute__((ext_vector_type(8))) unsigned short ushort8;

// ---------- helpers ----------
__device__ __forceinline__ float bf2f(unsigned short u) {
    unsigned int x = ((unsigned int)u) << 16;
    return __uint_as_float(x);
}
__device__ __forceinline__ unsigned short f2bf_bits(float f) {
    unsigned int x = __float_as_uint(f);
    unsigned int r = (x + 0x7fffu + ((x >> 16) & 1u)) >> 16;  // RNE
    return (unsigned short)r;
}

// ---------- Kernel 0: convert w1 (fp32 [256][512]) -> Wt (bf16 [512][256]) ----------
// Wt[j'][k] = (j' < 256) ? w1[j'][k] : w1[j'-256][256+k]
__global__ __launch_bounds__(256) void wt_conv_kernel(
    const float* __restrict__ w1, unsigned short* __restrict__ Wt)
{
    const int s = blockIdx.x * 256 + threadIdx.x;   // 0..131071
    const int j = s >> 9;
    const int kk = s & 511;
    const float v = w1[s];
    const int dst = (kk < D) ? (j * D + kk) : ((D + j) * D + (kk - D));
    Wt[dst] = f2bf_bits(v);
}

// ---------- Kernel 1: MFMA node projection ----------
// C[u, j'] = sum_k z[u,k] * Wt[j', k],  C bf16 [M][512]
__global__ __launch_bounds__(256, 2) void node_proj_mfma(
    const float* __restrict__ z, const unsigned short* __restrict__ Wt,
    unsigned short* __restrict__ C, int M)
{
    const int lane = threadIdx.x & 63;
    const int wave = threadIdx.x >> 6;      // 0..3
    const int m0   = blockIdx.x * 64;
    const int wn0  = wave * 128;            // this wave's column base

    const int r16 = lane & 15;
    const int g   = lane >> 4;              // 0..3
    const int kq  = g * 8;

    f32x4 acc[4][8];                         // [mt][nt]
    #pragma unroll
    for (int mt = 0; mt < 4; ++mt)
        #pragma unroll
        for (int nt = 0; nt < 8; ++nt)
            acc[mt][nt] = (f32x4){0.f, 0.f, 0.f, 0.f};

    const unsigned short* wtw = Wt + (size_t)(wn0 + r16) * D + kq;

    #pragma unroll
    for (int kt = 0; kt < 8; ++kt) {
        const int k0 = kt * 32;

        // A fragments: z fp32 -> bf16 in-register
        bf16x8 a[4];
        #pragma unroll
        for (int mt = 0; mt < 4; ++mt) {
            const int row = m0 + mt * 16 + r16;
            float4 v0 = make_float4(0.f, 0.f, 0.f, 0.f);
            float4 v1 = make_float4(0.f, 0.f, 0.f, 0.f);
            if (row < M) {
                const float* p = z + (size_t)row * D + k0 + kq;
                v0 = *(const float4*)p;
                v1 = *(const float4*)(p + 4);
            }
            bf16x8 t;
            t[0] = (__bf16)v0.x; t[1] = (__bf16)v0.y;
            t[2] = (__bf16)v0.z; t[3] = (__bf16)v0.w;
            t[4] = (__bf16)v1.x; t[5] = (__bf16)v1.y;
            t[6] = (__bf16)v1.z; t[7] = (__bf16)v1.w;
            a[mt] = t;
        }

        // B fragments from bf16 Wt (L2-resident), 16B per lane
        #pragma unroll
        for (int nt = 0; nt < 8; ++nt) {
            const ushort8 bu = *(const ushort8*)(wtw + (size_t)nt * 16 * D + k0);
            const bf16x8 b = __builtin_bit_cast(bf16x8, bu);
            #pragma unroll
            for (int mt = 0; mt < 4; ++mt)
                acc[mt][nt] = __builtin_amdgcn_mfma_f32_16x16x32_bf16(
                    b, a[mt], acc[mt][nt], 0, 0, 0);
        }
    }

    // Store: swapped operands => lane holds 4 consecutive C-columns for one row.
    // C[m0 + mt*16 + (lane&15)][wn0 + nt*16 + g*4 + i] = acc[mt][nt][i]
    #pragma unroll
    for (int mt = 0; mt < 4; ++mt) {
        const int row = m0 + mt * 16 + r16;
        if (row < M) {
            #pragma unroll
            for (int nt = 0; nt < 8; ++nt) {
                const int col = wn0 + nt * 16 + g * 4;
                ushort4 pk;
                pk.x = f2bf_bits(acc[mt][nt][0]);
                pk.y = f2bf_bits(acc[mt][nt][1]);
                pk.z = f2bf_bits(acc[mt][nt][2]);
                pk.w = f2bf_bits(acc[mt][nt][3]);
                *(ushort4*)(C + (size_t)row * TWOD + col) = pk;
            }
        }
    }
}

// ---------- Kernel 2: per-edge relu-dot ----------
// out[e] = sum_j relu(A[u,j] + B[v,j] + b1[j]) * w2[j] + b2
__global__ __launch_bounds__(256) void edge_kernel(
    const int* __restrict__ ei, const unsigned short* __restrict__ C,
    const float* __restrict__ b1, const float* __restrict__ w2,
    const float* __restrict__ b2, float* __restrict__ out, int E)
{
    const int lane = threadIdx.x & 63;
    const int wid  = (blockIdx.x * blockDim.x + threadIdx.x) >> 6;
    const int nw   = (gridDim.x * blockDim.x) >> 6;
    const int j0   = lane * 4;

    const float4 w2v = *(const float4*)(w2 + j0);
    const float4 b1v = *(const float4*)(b1 + j0);
    const float  b2s = b2[0];

    for (int e = wid; e < E; e += nw) {
        const int u = ei[e];
        const int v = ei[E + e];

        const ushort4 ua = *(const ushort4*)(C + (size_t)u * TWOD + j0);
        const ushort4 ub = *(const ushort4*)(C + (size_t)v * TWOD + D + j0);

        float s = 0.f;
        s += fmaxf(bf2f(ua.x) + bf2f(ub.x) + b1v.x, 0.f) * w2v.x;
        s += fmaxf(bf2f(ua.y) + bf2f(ub.y) + b1v.y, 0.f) * w2v.y;
        s += fmaxf(bf2f(ua.z) + bf2f(ub.z) + b1v.z, 0.f) * w2v.z;
        s += fmaxf(bf2f(ua.w) + bf2f(ub.w) + b1v.w, 0.f) * w2v.w;

        #pragma unroll
        for (int off = 32; off; off >>= 1)
            s += __shfl_xor(s, off);

        if (lane == 0) out[e] = s + b2s;
    }
}

extern "C" void kernel_launch(void* const* d_in, const int* in_sizes, int n_in,
                              void* d_out, int out_size, void* d_ws, size_t ws_size,
                              hipStream_t stream) {
    const float* z  = (const float*)d_in[0];
    const int*   ei = (const int*)d_in[1];
    const float* w1 = (const float*)d_in[2];
    const float* b1 = (const float*)d_in[3];
    const float* w2 = (const float*)d_in[4];
    const float* b2 = (const float*)d_in[5];
    float* out = (float*)d_out;

    const int M = in_sizes[0] / D;   // 50000 nodes
    const int E = in_sizes[1] / 2;   // 320000 edges

    unsigned short* C  = (unsigned short*)d_ws;   // M*512 bf16 = 51.2 MB
    unsigned short* Wt = (unsigned short*)d_out;  // 256 KB scratch inside d_out (1.28 MB);
                                                  // consumed by GEMM, then overwritten by edge_kernel

    wt_conv_kernel<<<512, 256, 0, stream>>>(w1, Wt);

    node_proj_mfma<<<(M + 63) / 64, 256, 0, stream>>>(z, Wt, C, M);

    edge_kernel<<<4096, 256, 0, stream>>>(ei, C, b1, w2, b2, out, E);
}